// Round 2
// baseline (1114.958 us; speedup 1.0000x reference)
//
#include <hip/hip_runtime.h>
#include <hip/hip_bf16.h>

// Problem constants (fixed by reference setup_inputs)
#define S_ROWS 4096
#define Q_ROWS 8192
#define DIM 256
#define N_SEL 19      // selection events (20 scan steps; step t consumes selection t-1)
#define COLSPLIT 8    // phase-B column splits (4096/8 = 512 cols per block)
#define NB 32         // iter_step blocks
#define RPB 256       // query rows per iter_step block

// Workspace layout (in floats)
#define WS_INV_Q 0
#define WS_QQ    (WS_INV_Q + Q_ROWS)
#define WS_INV_S (WS_QQ + Q_ROWS)
#define WS_PP    (WS_INV_S + S_ROWS)
#define WS_TOP3  (WS_PP + S_ROWS)                    // [Q_ROWS][4]
#define WS_TOP3P (WS_TOP3 + Q_ROWS * 4)              // [COLSPLIT][Q_ROWS][4]
#define WS_SCORES (WS_TOP3P + COLSPLIT * Q_ROWS * 4) // [2][Q_ROWS] u-scores (inf = known)
#define WS_BMIN  (WS_SCORES + 2 * Q_ROWS)            // [N_SEL][NB] per-block mins

// ---------------------------------------------------------------------------
// Row L2-norms: inv[r] = 1/||x_r||, ssq[r] = sum((x_r * inv)^2)
__global__ void norm_rows(const float* __restrict__ x, float* __restrict__ inv,
                          float* __restrict__ ssq, int nrows) {
    int w = (blockIdx.x * blockDim.x + threadIdx.x) >> 6;
    int lane = threadIdx.x & 63;
    if (w >= nrows) return;
    float4 v = reinterpret_cast<const float4*>(x + (size_t)w * DIM)[lane];
    float s = v.x * v.x + v.y * v.y + v.z * v.z + v.w * v.w;
#pragma unroll
    for (int o = 1; o < 64; o <<= 1) s += __shfl_xor(s, o, 64);
    float invn = 1.0f / sqrtf(s);
    float t = v.x * invn; float u = t * t;
    t = v.y * invn; u += t * t;
    t = v.z * invn; u += t * t;
    t = v.w * invn; u += t * t;
#pragma unroll
    for (int o = 1; o < 64; o <<= 1) u += __shfl_xor(u, o, 64);
    if (lane == 0) { inv[w] = invn; ssq[w] = u; }
}

// ---------------------------------------------------------------------------
// Second output = ones
__global__ void init_out(float* __restrict__ out, int n_extra) {
    int t = blockIdx.x * blockDim.x + threadIdx.x;
    if (t < n_extra) out[Q_ROWS + t] = 1.0f;
}

// ---------------------------------------------------------------------------
// Phase B: fused fp32 GEMM (qf_norm . sf_norm^T) + per-row top-3 of
// dist = sqrt(max(qq + pp - 2*dot, 1e-12)). Grid: 64 rowblocks x COLSPLIT.
__launch_bounds__(256, 2)
__global__ void knn_support_kernel(const float* __restrict__ qf, const float* __restrict__ sf,
                                   const float* __restrict__ inv_q, const float* __restrict__ inv_s,
                                   const float* __restrict__ qq, const float* __restrict__ pp,
                                   float* __restrict__ top3part) {
    __shared__ __align__(16) float smem[2 * 128 * 36];
    float (*As)[36] = reinterpret_cast<float(*)[36]>(smem);
    float (*Bs)[36] = reinterpret_cast<float(*)[36]>(smem + 128 * 36);

    int bid = blockIdx.x;
    int rb = (bid & 63) * 128;   // row block base
    int cs = bid >> 6;           // column split 0..7
    int tid = threadIdx.x;
    int tx = tid & 15, ty = tid >> 4;

    float t3[8][3];
#pragma unroll
    for (int i = 0; i < 8; ++i) t3[i][0] = t3[i][1] = t3[i][2] = INFINITY;

    for (int ch = 0; ch < 4; ++ch) {
        int cb = cs * 512 + ch * 128;
        float acc[8][8];
#pragma unroll
        for (int i = 0; i < 8; ++i)
#pragma unroll
            for (int j = 0; j < 8; ++j) acc[i][j] = 0.0f;

        for (int kt = 0; kt < 8; ++kt) {
#pragma unroll
            for (int q = 0; q < 4; ++q) {
                int idx = q * 256 + tid;
                int row = idx >> 3, f4 = idx & 7;
                float4 a = *reinterpret_cast<const float4*>(qf + (size_t)(rb + row) * DIM + kt * 32 + f4 * 4);
                float sa = inv_q[rb + row];
                As[row][f4 * 4 + 0] = a.x * sa; As[row][f4 * 4 + 1] = a.y * sa;
                As[row][f4 * 4 + 2] = a.z * sa; As[row][f4 * 4 + 3] = a.w * sa;
                float4 b = *reinterpret_cast<const float4*>(sf + (size_t)(cb + row) * DIM + kt * 32 + f4 * 4);
                float sb = inv_s[cb + row];
                Bs[row][f4 * 4 + 0] = b.x * sb; Bs[row][f4 * 4 + 1] = b.y * sb;
                Bs[row][f4 * 4 + 2] = b.z * sb; Bs[row][f4 * 4 + 3] = b.w * sb;
            }
            __syncthreads();
#pragma unroll
            for (int kk = 0; kk < 32; kk += 4) {
                float4 av[8], bv[8];
#pragma unroll
                for (int i = 0; i < 8; ++i) av[i] = *reinterpret_cast<const float4*>(&As[ty + 16 * i][kk]);
#pragma unroll
                for (int j = 0; j < 8; ++j) bv[j] = *reinterpret_cast<const float4*>(&Bs[tx + 16 * j][kk]);
#pragma unroll
                for (int i = 0; i < 8; ++i)
#pragma unroll
                    for (int j = 0; j < 8; ++j) {
                        acc[i][j] += av[i].x * bv[j].x;
                        acc[i][j] += av[i].y * bv[j].y;
                        acc[i][j] += av[i].z * bv[j].z;
                        acc[i][j] += av[i].w * bv[j].w;
                    }
            }
            __syncthreads();
        }
#pragma unroll
        for (int i = 0; i < 8; ++i) {
            float qqr = qq[rb + ty + 16 * i];
#pragma unroll
            for (int j = 0; j < 8; ++j) {
                float d2 = qqr + pp[cb + tx + 16 * j] - 2.0f * acc[i][j];
                float d = sqrtf(fmaxf(d2, 1e-12f));
                float mx = fmaxf(fmaxf(t3[i][0], t3[i][1]), t3[i][2]);
                if (d < mx) {
                    if (t3[i][0] == mx) t3[i][0] = d;
                    else if (t3[i][1] == mx) t3[i][1] = d;
                    else t3[i][2] = d;
                }
            }
        }
        __syncthreads();
    }

    // merge per-row top3 across the 16 tx lanes
#pragma unroll
    for (int i = 0; i < 8; ++i) {
        int row = ty + 16 * i;
        smem[(row * 16 + tx) * 3 + 0] = t3[i][0];
        smem[(row * 16 + tx) * 3 + 1] = t3[i][1];
        smem[(row * 16 + tx) * 3 + 2] = t3[i][2];
    }
    __syncthreads();
    if (tid < 128) {
        float b0 = INFINITY, b1 = INFINITY, b2 = INFINITY;
        for (int t = 0; t < 48; ++t) {
            float d = smem[tid * 48 + t];
            float mx = fmaxf(fmaxf(b0, b1), b2);
            if (d < mx) {
                if (b0 == mx) b0 = d;
                else if (b1 == mx) b1 = d;
                else b2 = d;
            }
        }
        float* dst = top3part + ((size_t)cs * Q_ROWS + rb + tid) * 4;
        dst[0] = b0; dst[1] = b1; dst[2] = b2; dst[3] = 0.0f;
    }
}

// ---------------------------------------------------------------------------
// Merge the COLSPLIT partial top-3s into one top-3 per row.
__global__ void merge_top3(const float* __restrict__ top3part, float* __restrict__ top3) {
    int row = blockIdx.x * blockDim.x + threadIdx.x;
    if (row >= Q_ROWS) return;
    float b0 = INFINITY, b1 = INFINITY, b2 = INFINITY;
#pragma unroll
    for (int cs = 0; cs < COLSPLIT; ++cs) {
        const float* p = top3part + ((size_t)cs * Q_ROWS + row) * 4;
#pragma unroll
        for (int k = 0; k < 3; ++k) {
            float d = p[k];
            float mx = fmaxf(fmaxf(b0, b1), b2);
            if (d < mx) {
                if (b0 == mx) b0 = d;
                else if (b1 == mx) b1 = d;
                else b2 = d;
            }
        }
    }
    float* dst = top3 + (size_t)row * 4;
    dst[0] = b0; dst[1] = b1; dst[2] = b2; dst[3] = 0.0f;
}

// ---------------------------------------------------------------------------
// Phase C: one scan step. The kernel-launch boundary is the grid sync.
//   phase 1 (t>0): consume publication t-1 -> kth, selected set; update own
//                  rows' top-3 vs each selected column.
//   phase 2 (t<19): publish u-scores (inf = known) + per-block min for step t.
//   t==19: write final output 1 - mean(top3).
// Cross-kernel locations are write-once-per-t (scores double-buffered, bmins
// indexed by t), so replays are race-free and idempotent.
__global__ void iter_step(const float* __restrict__ qf, const float* __restrict__ inv_q,
                          const float* __restrict__ qq, float* __restrict__ top3,
                          float* __restrict__ scores, float* __restrict__ bmins,
                          float* __restrict__ out, int t) {
    __shared__ float t3s[RPB][3];
    __shared__ float invs[RPB], qqs[RPB];
    __shared__ __align__(16) float qfc[DIM];
    __shared__ int lidx[RPB];
    __shared__ int lcnt;
    __shared__ float mins32[NB];
    __shared__ float kth_s;
    __shared__ float wmin4[4];

    int tid = threadIdx.x;
    int bid = blockIdx.x;
    int rbase = bid * RPB;
    int lane = tid & 63, wv = tid >> 6;

    {
        const float* p = top3 + (size_t)(rbase + tid) * 4;
        t3s[tid][0] = p[0]; t3s[tid][1] = p[1]; t3s[tid][2] = p[2];
        invs[tid] = inv_q[rbase + tid];
        qqs[tid] = qq[rbase + tid];
    }
    if (tid == 0) lcnt = 0;
    __syncthreads();

    float kth = 0.0f;
    if (t > 0) {
        // kth = min over the 32 block-mins published at t-1
        if (tid < NB) mins32[tid] = bmins[(t - 1) * NB + tid];
        __syncthreads();
        if (tid == 0) {
            float v = mins32[0];
            for (int i = 1; i < NB; ++i) v = fminf(v, mins32[i]);
            kth_s = v;
        }
        __syncthreads();
        kth = kth_s;

        // selected rows: u-score(t-1) <= kth (known rows are inf -> excluded)
        const float* prev = scores + ((t - 1) & 1) * Q_ROWS;
        for (int r = tid; r < Q_ROWS; r += RPB) {
            if (prev[r] <= kth) {
                int p = atomicAdd(&lcnt, 1);
                if (p < RPB) lidx[p] = r;
            }
        }
        __syncthreads();
        int m = lcnt < RPB ? lcnt : RPB;

        for (int jj = 0; jj < m; ++jj) {
            int c = lidx[jj];
            qfc[tid] = qf[(size_t)c * DIM + tid] * inv_q[c];
            __syncthreads();
            float qqc = qq[c];
            // 4 waves x 64 rows each; wave-owned rows -> no t3s race
            for (int rr = 0; rr < 64; ++rr) {
                int row = wv * 64 + rr;
                float4 v = *reinterpret_cast<const float4*>(qf + (size_t)(rbase + row) * DIM + lane * 4);
                float4 w4 = *reinterpret_cast<const float4*>(qfc + lane * 4);
                float d = v.x * w4.x + v.y * w4.y + v.z * w4.z + v.w * w4.w;
#pragma unroll
                for (int o = 1; o < 64; o <<= 1) d += __shfl_xor(d, o, 64);
                if (lane == 0) {
                    d *= invs[row];
                    float d2 = qqs[row] + qqc - 2.0f * d;
                    float dist = sqrtf(fmaxf(d2, 1e-12f));
                    float mx = fmaxf(fmaxf(t3s[row][0], t3s[row][1]), t3s[row][2]);
                    if (dist < mx) {
                        if (t3s[row][0] == mx) t3s[row][0] = dist;
                        else if (t3s[row][1] == mx) t3s[row][1] = dist;
                        else t3s[row][2] = dist;
                    }
                }
            }
            __syncthreads();
        }
    }
    __syncthreads();

    float sc = (t3s[tid][0] + t3s[tid][1] + t3s[tid][2]) * (1.0f / 3.0f);
    if (t == N_SEL) {
        out[rbase + tid] = 1.0f - sc;
        return;
    }

    bool kn = false;
    if (t > 0) {
        float pv = scores[((t - 1) & 1) * Q_ROWS + rbase + tid];
        kn = (pv == INFINITY) || (pv <= kth);
    }
    float u = kn ? INFINITY : sc;
    scores[(t & 1) * Q_ROWS + rbase + tid] = u;

    float mn = u;
#pragma unroll
    for (int o = 1; o < 64; o <<= 1) mn = fminf(mn, __shfl_xor(mn, o, 64));
    if (lane == 0) wmin4[wv] = mn;
    // write back updated top-3 for the next step
    if (t > 0) {
        float* p = top3 + (size_t)(rbase + tid) * 4;
        p[0] = t3s[tid][0]; p[1] = t3s[tid][1]; p[2] = t3s[tid][2];
    }
    __syncthreads();
    if (tid == 0)
        bmins[t * NB + bid] = fminf(fminf(wmin4[0], wmin4[1]), fminf(wmin4[2], wmin4[3]));
}

// ---------------------------------------------------------------------------
extern "C" void kernel_launch(void* const* d_in, const int* in_sizes, int n_in,
                              void* d_out, int out_size, void* d_ws, size_t ws_size,
                              hipStream_t stream) {
    const float* sfeat = (const float*)d_in[0];
    const float* qfeat = (const float*)d_in[2];
    float* out = (float*)d_out;

    float* ws = (float*)d_ws;
    float* inv_q  = ws + WS_INV_Q;
    float* qq     = ws + WS_QQ;
    float* inv_s  = ws + WS_INV_S;
    float* pp     = ws + WS_PP;
    float* top3   = ws + WS_TOP3;
    float* top3p  = ws + WS_TOP3P;
    float* scores = ws + WS_SCORES;
    float* bmins  = ws + WS_BMIN;

    int n_extra = out_size - Q_ROWS;
    if (n_extra < 0) n_extra = 0;

    norm_rows<<<Q_ROWS * 64 / 256, 256, 0, stream>>>(qfeat, inv_q, qq, Q_ROWS);
    norm_rows<<<S_ROWS * 64 / 256, 256, 0, stream>>>(sfeat, inv_s, pp, S_ROWS);
    if (n_extra > 0)
        init_out<<<(n_extra + 255) / 256, 256, 0, stream>>>(out, n_extra);
    knn_support_kernel<<<64 * COLSPLIT, 256, 0, stream>>>(qfeat, sfeat, inv_q, inv_s, qq, pp, top3p);
    merge_top3<<<Q_ROWS / 256, 256, 0, stream>>>(top3p, top3);

    for (int t = 0; t <= N_SEL; ++t)
        iter_step<<<NB, RPB, 0, stream>>>(qfeat, inv_q, qq, top3, scores, bmins, out, t);
}

// Round 3
// 814.662 us; speedup vs baseline: 1.3686x; 1.3686x over previous
//
#include <hip/hip_runtime.h>
#include <hip/hip_bf16.h>

// Problem constants (fixed by reference setup_inputs)
#define S_ROWS 4096
#define Q_ROWS 8192
#define DIM 256
#define N_SEL 19       // selection events (20 scan steps; step t consumes selection t-1)
#define COLSPLIT 16    // phase-B column splits (4096/16 = 256 cols per block)
#define CH_ITERS 2     // 256 cols / 128-col tiles
#define CB 32          // phase-C blocks
#define CT 512         // phase-C threads per block
#define CROWS 256      // phase-C rows per block (Q_ROWS / CB)
#define LCAP 64        // selected-list capacity per iteration

// Workspace layout (in floats)
#define WS_INV_Q 0
#define WS_QQ    (WS_INV_Q + Q_ROWS)
#define WS_INV_S (WS_QQ + Q_ROWS)
#define WS_PP    (WS_INV_S + S_ROWS)
#define WS_TOP3  (WS_PP + S_ROWS)                    // [Q_ROWS][4]
#define WS_TOP3P (WS_TOP3 + Q_ROWS * 4)              // [COLSPLIT][Q_ROWS][4]
#define WS_SCORES (WS_TOP3P + COLSPLIT * Q_ROWS * 4) // [2][Q_ROWS] u-scores (inf = known)
#define WS_KTH   (WS_SCORES + 2 * Q_ROWS)            // unsigned [32]
#define WS_BAR   (WS_KTH + 32)                       // unsigned [32] barrier counters

// ---------------------------------------------------------------------------
// Row L2-norms: inv[r] = 1/||x_r||, ssq[r] = sum((x_r * inv)^2)
__global__ void norm_rows(const float* __restrict__ x, float* __restrict__ inv,
                          float* __restrict__ ssq, int nrows) {
    int w = (blockIdx.x * blockDim.x + threadIdx.x) >> 6;
    int lane = threadIdx.x & 63;
    if (w >= nrows) return;
    float4 v = reinterpret_cast<const float4*>(x + (size_t)w * DIM)[lane];
    float s = v.x * v.x + v.y * v.y + v.z * v.z + v.w * v.w;
#pragma unroll
    for (int o = 1; o < 64; o <<= 1) s += __shfl_xor(s, o, 64);
    float invn = 1.0f / sqrtf(s);
    float t = v.x * invn; float u = t * t;
    t = v.y * invn; u += t * t;
    t = v.z * invn; u += t * t;
    t = v.w * invn; u += t * t;
#pragma unroll
    for (int o = 1; o < 64; o <<= 1) u += __shfl_xor(u, o, 64);
    if (lane == 0) { inv[w] = invn; ssq[w] = u; }
}

// ---------------------------------------------------------------------------
// Per-call init: kth slots to +inf, barrier counters to 0, extra outputs to 1.
__global__ void init_ws(unsigned* __restrict__ kth, unsigned* __restrict__ bar,
                        float* __restrict__ out, int n_extra) {
    int t = blockIdx.x * blockDim.x + threadIdx.x;
    if (t < 32) { kth[t] = 0x7F800000u; bar[t] = 0u; }
    if (t < n_extra) out[Q_ROWS + t] = 1.0f;
}

// ---------------------------------------------------------------------------
// Phase B: fused fp32 GEMM (qf_norm . sf_norm^T) + per-row top-3 of
// dist = sqrt(max(qq + pp - 2*dot, 1e-12)). Grid: 64 rowblocks x COLSPLIT.
__launch_bounds__(256, 2)
__global__ void knn_support_kernel(const float* __restrict__ qf, const float* __restrict__ sf,
                                   const float* __restrict__ inv_q, const float* __restrict__ inv_s,
                                   const float* __restrict__ qq, const float* __restrict__ pp,
                                   float* __restrict__ top3part) {
    __shared__ __align__(16) float smem[2 * 128 * 36];
    float (*As)[36] = reinterpret_cast<float(*)[36]>(smem);
    float (*Bs)[36] = reinterpret_cast<float(*)[36]>(smem + 128 * 36);

    int bid = blockIdx.x;
    int rb = (bid & 63) * 128;   // row block base
    int cs = bid >> 6;           // column split 0..COLSPLIT-1
    int tid = threadIdx.x;
    int tx = tid & 15, ty = tid >> 4;

    float t3[8][3];
#pragma unroll
    for (int i = 0; i < 8; ++i) t3[i][0] = t3[i][1] = t3[i][2] = INFINITY;

    for (int ch = 0; ch < CH_ITERS; ++ch) {
        int cb = cs * (S_ROWS / COLSPLIT) + ch * 128;
        float acc[8][8];
#pragma unroll
        for (int i = 0; i < 8; ++i)
#pragma unroll
            for (int j = 0; j < 8; ++j) acc[i][j] = 0.0f;

        for (int kt = 0; kt < 8; ++kt) {
#pragma unroll
            for (int q = 0; q < 4; ++q) {
                int idx = q * 256 + tid;
                int row = idx >> 3, f4 = idx & 7;
                float4 a = *reinterpret_cast<const float4*>(qf + (size_t)(rb + row) * DIM + kt * 32 + f4 * 4);
                float sa = inv_q[rb + row];
                As[row][f4 * 4 + 0] = a.x * sa; As[row][f4 * 4 + 1] = a.y * sa;
                As[row][f4 * 4 + 2] = a.z * sa; As[row][f4 * 4 + 3] = a.w * sa;
                float4 b = *reinterpret_cast<const float4*>(sf + (size_t)(cb + row) * DIM + kt * 32 + f4 * 4);
                float sb = inv_s[cb + row];
                Bs[row][f4 * 4 + 0] = b.x * sb; Bs[row][f4 * 4 + 1] = b.y * sb;
                Bs[row][f4 * 4 + 2] = b.z * sb; Bs[row][f4 * 4 + 3] = b.w * sb;
            }
            __syncthreads();
#pragma unroll
            for (int kk = 0; kk < 32; kk += 4) {
                float4 av[8], bv[8];
#pragma unroll
                for (int i = 0; i < 8; ++i) av[i] = *reinterpret_cast<const float4*>(&As[ty + 16 * i][kk]);
#pragma unroll
                for (int j = 0; j < 8; ++j) bv[j] = *reinterpret_cast<const float4*>(&Bs[tx + 16 * j][kk]);
#pragma unroll
                for (int i = 0; i < 8; ++i)
#pragma unroll
                    for (int j = 0; j < 8; ++j) {
                        acc[i][j] += av[i].x * bv[j].x;
                        acc[i][j] += av[i].y * bv[j].y;
                        acc[i][j] += av[i].z * bv[j].z;
                        acc[i][j] += av[i].w * bv[j].w;
                    }
            }
            __syncthreads();
        }
#pragma unroll
        for (int i = 0; i < 8; ++i) {
            float qqr = qq[rb + ty + 16 * i];
#pragma unroll
            for (int j = 0; j < 8; ++j) {
                float d2 = qqr + pp[cb + tx + 16 * j] - 2.0f * acc[i][j];
                float d = sqrtf(fmaxf(d2, 1e-12f));
                float mx = fmaxf(fmaxf(t3[i][0], t3[i][1]), t3[i][2]);
                if (d < mx) {
                    if (t3[i][0] == mx) t3[i][0] = d;
                    else if (t3[i][1] == mx) t3[i][1] = d;
                    else t3[i][2] = d;
                }
            }
        }
        __syncthreads();
    }

    // merge per-row top3 across the 16 tx lanes
#pragma unroll
    for (int i = 0; i < 8; ++i) {
        int row = ty + 16 * i;
        smem[(row * 16 + tx) * 3 + 0] = t3[i][0];
        smem[(row * 16 + tx) * 3 + 1] = t3[i][1];
        smem[(row * 16 + tx) * 3 + 2] = t3[i][2];
    }
    __syncthreads();
    if (tid < 128) {
        float b0 = INFINITY, b1 = INFINITY, b2 = INFINITY;
        for (int t = 0; t < 48; ++t) {
            float d = smem[tid * 48 + t];
            float mx = fmaxf(fmaxf(b0, b1), b2);
            if (d < mx) {
                if (b0 == mx) b0 = d;
                else if (b1 == mx) b1 = d;
                else b2 = d;
            }
        }
        float* dst = top3part + ((size_t)cs * Q_ROWS + rb + tid) * 4;
        dst[0] = b0; dst[1] = b1; dst[2] = b2; dst[3] = 0.0f;
    }
}

// ---------------------------------------------------------------------------
// Merge the COLSPLIT partial top-3s into one top-3 per row.
__global__ void merge_top3(const float* __restrict__ top3part, float* __restrict__ top3) {
    int row = blockIdx.x * blockDim.x + threadIdx.x;
    if (row >= Q_ROWS) return;
    float b0 = INFINITY, b1 = INFINITY, b2 = INFINITY;
#pragma unroll
    for (int cs = 0; cs < COLSPLIT; ++cs) {
        const float* p = top3part + ((size_t)cs * Q_ROWS + row) * 4;
#pragma unroll
        for (int k = 0; k < 3; ++k) {
            float d = p[k];
            float mx = fmaxf(fmaxf(b0, b1), b2);
            if (d < mx) {
                if (b0 == mx) b0 = d;
                else if (b1 == mx) b1 = d;
                else b2 = d;
            }
        }
    }
    float* dst = top3 + (size_t)row * 4;
    dst[0] = b0; dst[1] = b1; dst[2] = b2; dst[3] = 0.0f;
}

// ---------------------------------------------------------------------------
// Phase C: all 20 scan steps in ONE cooperative kernel, one lightweight
// agent-scope barrier per iteration. Block state (top3, inv, qq) lives in LDS
// for the whole kernel. Cross-block traffic per iteration: u-scores
// (double-buffered), kth[t] (atomicMin), bar[t] (barrier slot).
__global__ void iterate_select(const float* __restrict__ qf, const float* __restrict__ inv_q,
                               const float* __restrict__ qq, const float* __restrict__ top3,
                               float* __restrict__ scores, unsigned* __restrict__ kth,
                               unsigned* __restrict__ bar, float* __restrict__ out) {
    __shared__ float t3s[CROWS][3];
    __shared__ float invs[CROWS], qqs[CROWS];
    __shared__ __align__(16) float qfc[DIM];
    __shared__ int lidx[LCAP];
    __shared__ int lcnt;
    __shared__ float wmins[CT / 64];

    int tid = threadIdx.x;
    int rbase = blockIdx.x * CROWS;
    int lane = tid & 63, wv = tid >> 6;

    for (int r = tid; r < CROWS; r += CT) {
        const float* p = top3 + (size_t)(rbase + r) * 4;
        t3s[r][0] = p[0]; t3s[r][1] = p[1]; t3s[r][2] = p[2];
        invs[r] = inv_q[rbase + r];
        qqs[r] = qq[rbase + r];
    }
    __syncthreads();

    float kth_v = INFINITY;
    for (int t = 0; t <= N_SEL; ++t) {
        if (t > 0) {
            kth_v = __uint_as_float(
                __hip_atomic_load(&kth[t - 1], __ATOMIC_RELAXED, __HIP_MEMORY_SCOPE_AGENT));
            if (tid == 0) lcnt = 0;
            __syncthreads();
            // every block independently derives the selected set (same data -> same set)
            const float* prev = scores + ((t - 1) & 1) * Q_ROWS;
            for (int r = tid; r < Q_ROWS; r += CT) {
                if (prev[r] <= kth_v) {
                    int p = atomicAdd(&lcnt, 1);
                    if (p < LCAP) lidx[p] = r;
                }
            }
            __syncthreads();
            int m = lcnt < LCAP ? lcnt : LCAP;
            for (int jj = 0; jj < m; ++jj) {
                int c = lidx[jj];
                if (tid < DIM) qfc[tid] = qf[(size_t)c * DIM + tid] * inv_q[c];
                __syncthreads();
                float qqc = qq[c];
                // 8 waves x 32 rows; products pre-scaled by inv so the c==r dot
                // bitwise-matches qq's shuffle tree (d2 -> exactly 0 -> clamp).
#pragma unroll 4
                for (int rr = 0; rr < CROWS / (CT / 64); ++rr) {
                    int row = wv * (CROWS / (CT / 64)) + rr;
                    float4 v = *reinterpret_cast<const float4*>(qf + (size_t)(rbase + row) * DIM + lane * 4);
                    float4 w4 = *reinterpret_cast<const float4*>(qfc + lane * 4);
                    float si = invs[row];
                    float d = (v.x * si) * w4.x + (v.y * si) * w4.y
                            + (v.z * si) * w4.z + (v.w * si) * w4.w;
#pragma unroll
                    for (int o = 1; o < 64; o <<= 1) d += __shfl_xor(d, o, 64);
                    if (lane == 0) {
                        float d2 = qqs[row] + qqc - 2.0f * d;
                        float dist = sqrtf(fmaxf(d2, 1e-12f));
                        float b0 = t3s[row][0], b1 = t3s[row][1], b2 = t3s[row][2];
                        float mx = fmaxf(fmaxf(b0, b1), b2);
                        if (dist < mx) {
                            if (b0 == mx) t3s[row][0] = dist;
                            else if (b1 == mx) t3s[row][1] = dist;
                            else t3s[row][2] = dist;
                        }
                    }
                }
                __syncthreads();
            }
        }

        if (t == N_SEL) {
            // final scores -> output (sorted-sum: deterministic under slot permutation)
            for (int r = tid; r < CROWS; r += CT) {
                float a = t3s[r][0], b = t3s[r][1], c = t3s[r][2];
                float lo = fminf(fminf(a, b), c);
                float hi = fmaxf(fmaxf(a, b), c);
                float md = fminf(fmaxf(a, b), fminf(fmaxf(b, c), fmaxf(a, c)));
                out[rbase + r] = 1.0f - ((lo + md) + hi) * (1.0f / 3.0f);
            }
            return;
        }

        // publish u-scores + contribute block min to kth[t]
        float u = INFINITY;
        if (tid < CROWS) {
            int r = tid;
            float a = t3s[r][0], b = t3s[r][1], c = t3s[r][2];
            float lo = fminf(fminf(a, b), c);
            float hi = fmaxf(fmaxf(a, b), c);
            float md = fminf(fmaxf(a, b), fminf(fmaxf(b, c), fmaxf(a, c)));
            float sc = ((lo + md) + hi) * (1.0f / 3.0f);
            bool kn = false;
            if (t > 0) {
                float pv = scores[((t - 1) & 1) * Q_ROWS + rbase + r];
                kn = (pv == INFINITY) || (pv <= kth_v);
            }
            u = kn ? INFINITY : sc;
            scores[(t & 1) * Q_ROWS + rbase + r] = u;
        }
        float mn = u;
#pragma unroll
        for (int o = 1; o < 64; o <<= 1) mn = fminf(mn, __shfl_xor(mn, o, 64));
        if (lane == 0) wmins[wv] = mn;
        __syncthreads();
        if (tid == 0) {
            float v = wmins[0];
#pragma unroll
            for (int i = 1; i < CT / 64; ++i) v = fminf(v, wmins[i]);
            atomicMin(&kth[t], __float_as_uint(v));   // device-scope by default
        }
        __syncthreads();
        // lightweight grid barrier: arrive (release) + spin (acquire), slot t
        if (tid == 0) {
            __hip_atomic_fetch_add(&bar[t], 1u, __ATOMIC_RELEASE, __HIP_MEMORY_SCOPE_AGENT);
            while (__hip_atomic_load(&bar[t], __ATOMIC_ACQUIRE, __HIP_MEMORY_SCOPE_AGENT) < CB)
                __builtin_amdgcn_s_sleep(8);
        }
        __syncthreads();
    }
}

// ---------------------------------------------------------------------------
extern "C" void kernel_launch(void* const* d_in, const int* in_sizes, int n_in,
                              void* d_out, int out_size, void* d_ws, size_t ws_size,
                              hipStream_t stream) {
    const float* sfeat = (const float*)d_in[0];
    const float* qfeat = (const float*)d_in[2];
    float* out = (float*)d_out;

    float* ws = (float*)d_ws;
    float* inv_q  = ws + WS_INV_Q;
    float* qq     = ws + WS_QQ;
    float* inv_s  = ws + WS_INV_S;
    float* pp     = ws + WS_PP;
    float* top3   = ws + WS_TOP3;
    float* top3p  = ws + WS_TOP3P;
    float* scores = ws + WS_SCORES;
    unsigned* kth = (unsigned*)(ws + WS_KTH);
    unsigned* bar = (unsigned*)(ws + WS_BAR);

    int n_extra = out_size - Q_ROWS;
    if (n_extra < 0) n_extra = 0;

    norm_rows<<<Q_ROWS * 64 / 256, 256, 0, stream>>>(qfeat, inv_q, qq, Q_ROWS);
    norm_rows<<<S_ROWS * 64 / 256, 256, 0, stream>>>(sfeat, inv_s, pp, S_ROWS);
    init_ws<<<32, 256, 0, stream>>>(kth, bar, out, n_extra);
    knn_support_kernel<<<64 * COLSPLIT, 256, 0, stream>>>(qfeat, sfeat, inv_q, inv_s, qq, pp, top3p);
    merge_top3<<<Q_ROWS / 256, 256, 0, stream>>>(top3p, top3);

    const float* a0 = qfeat; const float* a1 = inv_q; const float* a2 = qq;
    const float* a3 = top3; float* a4 = scores; unsigned* a5 = kth; unsigned* a6 = bar;
    float* a7 = out;
    void* cargs[] = {&a0, &a1, &a2, &a3, &a4, &a5, &a6, &a7};
    hipLaunchCooperativeKernel(iterate_select, dim3(CB), dim3(CT), cargs, 0, stream);
}